// Round 8
// baseline (5426.005 us; speedup 1.0000x reference)
//
#include <hip/hip_runtime.h>
#include <hip/hip_bf16.h>
#include <math.h>

#define SEQ   1024
#define BATCH 256
#define IND   256
#define HID   256
#define NGATE 4

// ws layout:
//   wb : bf16 [2 parts][4 gates][256 j][256 k], swizzled rows (1 MiB) @ 0
//   hr : bf16 regions [2 slots][16 g][16 J][16 b][16 j], LSB-stamped
//        (512 B per region, single writer each; 256 KiB total)  @ 1 MiB
#define WB_BYTES   (2 * NGATE * HID * 256 * 2)
#define REG_BYTES  512

typedef float  f32x4  __attribute__((ext_vector_type(4)));
typedef short  bf16x8 __attribute__((ext_vector_type(8)));
typedef unsigned long long u64;

#define LSB_MASK 0x0001000100010001ULL

__device__ __forceinline__ short f2bf(float x) {
    __hip_bfloat16 h = __float2bfloat16(x);
    return *reinterpret_cast<short*>(&h);
}

__device__ __forceinline__ bf16x8 pack8(const float4& a, const float4& b) {
    union { short sh[8]; bf16x8 v; } u;
    u.sh[0] = f2bf(a.x); u.sh[1] = f2bf(a.y); u.sh[2] = f2bf(a.z); u.sh[3] = f2bf(a.w);
    u.sh[4] = f2bf(b.x); u.sh[5] = f2bf(b.y); u.sh[6] = f2bf(b.z); u.sh[7] = f2bf(b.w);
    return u.v;
}

__device__ __forceinline__ void gload_lds16(const void* g, void* l) {
    __builtin_amdgcn_global_load_lds(
        (const __attribute__((address_space(1))) unsigned int*)g,
        (__attribute__((address_space(3))) unsigned int*)l, 16, 0, 0);
}

__device__ __forceinline__ float sigmoid_f(float z) {
    return 1.f / (1.f + __expf(-z));
}
__device__ __forceinline__ float tanh_f(float v) {
    return 2.f / (1.f + __expf(-2.f * v)) - 1.f;
}

__device__ __forceinline__ bool stamp_ok(u64 q0, u64 q1, u64 ee) {
    return ((((q0 ^ ee) | (q1 ^ ee)) & LSB_MASK) == 0ULL);
}

// ---------------- prep kernels (unchanged from R7) ----------------

__global__ __launch_bounds__(256) void prep_w(
    const float* __restrict__ Wf, const float* __restrict__ Wi,
    const float* __restrict__ Wg, const float* __restrict__ Wo,
    unsigned char* __restrict__ wb)
{
    int chunk = blockIdx.x * 256 + threadIdx.x;   // 65536 chunks of 8 floats
    int g  = chunk >> 14;
    int jj = (chunk >> 6) & 255;
    int k0 = (chunk & 63) * 8;
    int p  = k0 >> 8;
    int kk = k0 & 255;
    const float* W = (g == 0) ? Wf : (g == 1) ? Wi : (g == 2) ? Wg : Wo;
    const float* src = W + (size_t)jj * 512 + k0;
    float4 a = *reinterpret_cast<const float4*>(src);
    float4 b = *reinterpret_cast<const float4*>(src + 4);
    size_t dstrow = (size_t)((p * 4 + g) * 256 + jj);
    *reinterpret_cast<bf16x8*>(
        wb + dstrow * 512 + ((kk * 2) ^ ((jj & 7) << 4))) = pack8(a, b);
}

__global__ __launch_bounds__(256) void prep_h0(
    const float* __restrict__ h0, unsigned char* __restrict__ hr)
{
    int idx  = blockIdx.x * 256 + threadIdx.x;    // 32768 chunks of 8 B
    int slot = idx >> 14;
    int g    = (idx >> 10) & 15;
    int J    = (idx >> 6) & 15;
    int c    = idx & 63;
    int br   = c >> 2;
    int j4   = (c & 3) * 4;
    const float* src = h0 + (size_t)(g * 16 + br) * HID + J * 16 + j4;
    unsigned short v[4];
    #pragma unroll
    for (int i = 0; i < 4; ++i)
        v[i] = (unsigned short)((unsigned short)f2bf(src[i]) | 1u);
    u64 q = (u64)v[0] | ((u64)v[1] << 16) | ((u64)v[2] << 32) | ((u64)v[3] << 48);
    *reinterpret_cast<u64*>(
        hr + (size_t)((slot * 16 + g) * 16 + J) * REG_BYTES + c * 8) = q;
}

// ---------------- persistent sequence kernel ----------------
// 128 blocks x 64 threads. p = blk&7 (pair -> XCD under round-robin),
// J = blk>>3 (16 j-cols). Each block runs TWO independent recurrences:
// group A = p (rows 16p..), group B = p+8 (rows 16p+128..). W is shared:
// h-part W in registers (critical path), x-part W re-read from LDS each
// step (filler work inside the handoff-latency shadow). Per step:
//   [issue xA,xB,hA,hB loads] [phaseA_A from LDS-W] [phaseA_B]
//   [checkA->retry] [phaseB_A regs-W] [epiA: stamped h + out stores]
//   [checkB->retry] [phaseB_B] [epiB]
__global__ __launch_bounds__(64, 1) void lstm_seq(
    const float* __restrict__ x,  const float* __restrict__ c0,
    const float* __restrict__ bf_, const float* __restrict__ bi_,
    const float* __restrict__ bg_, const float* __restrict__ bo_,
    const unsigned char* __restrict__ wb, unsigned char* __restrict__ hr,
    float* __restrict__ out, float* __restrict__ hx, float* __restrict__ cxg)
{
    extern __shared__ __align__(16) unsigned char smem[];   // 64 KiB

    const int lane = threadIdx.x & 63;
    const int blk  = blockIdx.x;
    const int p_   = blk & 7;           // pair id == XCD (heuristic)
    const int J    = blk >> 3;          // j-tile 0..15
    const int j0   = J * 16;
    const int gA   = p_;
    const int gB   = p_ + 8;
    const int b0A  = gA * 16;
    const int b0B  = gB * 16;

    const int lrow = lane & 15;
    const int hi   = lane >> 4;
    const int j    = j0 + lrow;

    // ---- stage full W tile (64 KiB) into LDS once
    #pragma unroll
    for (int i = 0; i < 64; ++i) {
        gload_lds16(wb + ((size_t)((i >> 3) * 256 + j0 + (i & 7) * 2)) * 512
                       + lane * 16,
                    smem + i * 1024);
    }
    const float biasF = bf_[j], biasI = bi_[j], biasG = bg_[j], biasO = bo_[j];
    float cstA[4], cstB[4];
    #pragma unroll
    for (int r = 0; r < 4; ++r) {
        cstA[r] = c0[(b0A + hi * 4 + r) * HID + j];
        cstB[r] = c0[(b0B + hi * 4 + r) * HID + j];
    }
    __syncthreads();    // drains gload_lds

    // ---- h-part W fragments -> registers (128 VGPR): wf[kc][gate]
    const int bswz = (lrow & 7) << 4;
    bf16x8 wf[8][4];
    #pragma unroll
    for (int kc = 0; kc < 8; ++kc) {
        int wbyte = (kc * 64 + hi * 16) ^ bswz;
        #pragma unroll
        for (int gg = 0; gg < 4; ++gg)
            wf[kc][gg] = *reinterpret_cast<const bf16x8*>(
                smem + 32768 + gg * 8192 + lrow * 512 + wbyte);
    }
    // x-part W stays in LDS (smem + gate*8192), re-read every step.

    // h region pointers
    unsigned char* regcA[2] = {
        hr + (size_t)((0 * 16 + gA) * 16) * REG_BYTES,
        hr + (size_t)((1 * 16 + gA) * 16) * REG_BYTES };
    unsigned char* regcB[2] = {
        hr + (size_t)((0 * 16 + gB) * 16) * REG_BYTES,
        hr + (size_t)((1 * 16 + gB) * 16) * REG_BYTES };
    unsigned char* regpA[2] = { regcA[0] + J * REG_BYTES, regcA[1] + J * REG_BYTES };
    unsigned char* regpB[2] = { regcB[0] + J * REG_BYTES, regcB[1] + J * REG_BYTES };

    for (int s = 0; s < SEQ; ++s) {
        const u64 ee = (((unsigned)(s + 3) >> 1) & 1) ? LSB_MASK : 0ULL;
        const unsigned char* hsA = regcA[s & 1];
        const unsigned char* hsB = regcB[s & 1];

        // ---- issue x loads (A then B), then h loads (A then B).
        //      vmcnt in-order: phase A_A waits only on xA; h stays in flight.
        float4 xtA0[8], xtA1[8], xtB0[8], xtB1[8];
        {
            const float* xrA = x + ((size_t)s * BATCH + b0A + lrow) * IND;
            #pragma unroll
            for (int kc = 0; kc < 8; ++kc) {
                const float* pp = xrA + kc * 32 + hi * 8;
                xtA0[kc] = *reinterpret_cast<const float4*>(pp);
                xtA1[kc] = *reinterpret_cast<const float4*>(pp + 4);
            }
            const float* xrB = x + ((size_t)s * BATCH + b0B + lrow) * IND;
            #pragma unroll
            for (int kc = 0; kc < 8; ++kc) {
                const float* pp = xrB + kc * 32 + hi * 8;
                xtB0[kc] = *reinterpret_cast<const float4*>(pp);
                xtB1[kc] = *reinterpret_cast<const float4*>(pp + 4);
            }
        }
        __builtin_amdgcn_sched_barrier(0);
        u64 aq0[8], aq1[8], bq0[8], bq1[8];
        #pragma unroll
        for (int kc = 0; kc < 8; ++kc) {
            const u64* pp = reinterpret_cast<const u64*>(
                hsA + (2 * kc + (hi >> 1)) * REG_BYTES + lrow * 32 + (hi & 1) * 16);
            aq0[kc] = __hip_atomic_load(pp,     __ATOMIC_RELAXED, __HIP_MEMORY_SCOPE_AGENT);
            aq1[kc] = __hip_atomic_load(pp + 1, __ATOMIC_RELAXED, __HIP_MEMORY_SCOPE_AGENT);
        }
        #pragma unroll
        for (int kc = 0; kc < 8; ++kc) {
            const u64* pp = reinterpret_cast<const u64*>(
                hsB + (2 * kc + (hi >> 1)) * REG_BYTES + lrow * 32 + (hi & 1) * 16);
            bq0[kc] = __hip_atomic_load(pp,     __ATOMIC_RELAXED, __HIP_MEMORY_SCOPE_AGENT);
            bq1[kc] = __hip_atomic_load(pp + 1, __ATOMIC_RELAXED, __HIP_MEMORY_SCOPE_AGENT);
        }
        __builtin_amdgcn_sched_barrier(0);

        f32x4 aAF = {0.f,0.f,0.f,0.f}, aAI = {0.f,0.f,0.f,0.f};
        f32x4 aAG = {0.f,0.f,0.f,0.f}, aAO = {0.f,0.f,0.f,0.f};
        f32x4 aBF = {0.f,0.f,0.f,0.f}, aBI = {0.f,0.f,0.f,0.f};
        f32x4 aBG = {0.f,0.f,0.f,0.f}, aBO = {0.f,0.f,0.f,0.f};

        // ---- phase A_A: x-part MFMA, W from LDS (filler inside h RT)
        #pragma unroll
        for (int kc = 0; kc < 8; ++kc) {
            int wbyte = (kc * 64 + hi * 16) ^ bswz;
            const unsigned char* wr = smem + lrow * 512 + wbyte;
            bf16x8 vF = *reinterpret_cast<const bf16x8*>(wr);
            bf16x8 vI = *reinterpret_cast<const bf16x8*>(wr + 8192);
            bf16x8 vG = *reinterpret_cast<const bf16x8*>(wr + 16384);
            bf16x8 vO = *reinterpret_cast<const bf16x8*>(wr + 24576);
            bf16x8 af = pack8(xtA0[kc], xtA1[kc]);
            aAF = __builtin_amdgcn_mfma_f32_16x16x32_bf16(af, vF, aAF, 0, 0, 0);
            aAI = __builtin_amdgcn_mfma_f32_16x16x32_bf16(af, vI, aAI, 0, 0, 0);
            aAG = __builtin_amdgcn_mfma_f32_16x16x32_bf16(af, vG, aAG, 0, 0, 0);
            aAO = __builtin_amdgcn_mfma_f32_16x16x32_bf16(af, vO, aAO, 0, 0, 0);
        }
        // ---- phase A_B
        #pragma unroll
        for (int kc = 0; kc < 8; ++kc) {
            int wbyte = (kc * 64 + hi * 16) ^ bswz;
            const unsigned char* wr = smem + lrow * 512 + wbyte;
            bf16x8 vF = *reinterpret_cast<const bf16x8*>(wr);
            bf16x8 vI = *reinterpret_cast<const bf16x8*>(wr + 8192);
            bf16x8 vG = *reinterpret_cast<const bf16x8*>(wr + 16384);
            bf16x8 vO = *reinterpret_cast<const bf16x8*>(wr + 24576);
            bf16x8 bfr = pack8(xtB0[kc], xtB1[kc]);
            aBF = __builtin_amdgcn_mfma_f32_16x16x32_bf16(bfr, vF, aBF, 0, 0, 0);
            aBI = __builtin_amdgcn_mfma_f32_16x16x32_bf16(bfr, vI, aBI, 0, 0, 0);
            aBG = __builtin_amdgcn_mfma_f32_16x16x32_bf16(bfr, vG, aBG, 0, 0, 0);
            aBO = __builtin_amdgcn_mfma_f32_16x16x32_bf16(bfr, vO, aBO, 0, 0, 0);
        }

        // ---- check A stamps + retry
        {
            unsigned pend = 0;
            #pragma unroll
            for (int kc = 0; kc < 8; ++kc)
                if (!stamp_ok(aq0[kc], aq1[kc], ee)) pend |= (1u << kc);
            while (pend) {
                __builtin_amdgcn_s_sleep(1);
                #pragma unroll
                for (int kc = 0; kc < 8; ++kc) {
                    if (pend & (1u << kc)) {
                        const u64* pp = reinterpret_cast<const u64*>(
                            hsA + (2 * kc + (hi >> 1)) * REG_BYTES + lrow * 32 + (hi & 1) * 16);
                        aq0[kc] = __hip_atomic_load(pp,     __ATOMIC_RELAXED, __HIP_MEMORY_SCOPE_AGENT);
                        aq1[kc] = __hip_atomic_load(pp + 1, __ATOMIC_RELAXED, __HIP_MEMORY_SCOPE_AGENT);
                        if (stamp_ok(aq0[kc], aq1[kc], ee)) pend &= ~(1u << kc);
                    }
                }
            }
        }
        // ---- phase B_A: h-part MFMA from register W
        #pragma unroll
        for (int kc = 0; kc < 8; ++kc) {
            union { u64 q[2]; bf16x8 v; } u;
            u.q[0] = aq0[kc]; u.q[1] = aq1[kc];
            aAF = __builtin_amdgcn_mfma_f32_16x16x32_bf16(u.v, wf[kc][0], aAF, 0, 0, 0);
            aAI = __builtin_amdgcn_mfma_f32_16x16x32_bf16(u.v, wf[kc][1], aAI, 0, 0, 0);
            aAG = __builtin_amdgcn_mfma_f32_16x16x32_bf16(u.v, wf[kc][2], aAG, 0, 0, 0);
            aAO = __builtin_amdgcn_mfma_f32_16x16x32_bf16(u.v, wf[kc][3], aAO, 0, 0, 0);
        }
        // ---- epilogue A
        const unsigned short st = (unsigned short)((s >> 1) & 1);
        float* outp = out + (size_t)s * (BATCH * HID);
        {
            unsigned char* hd = regpA[(s + 1) & 1];
            #pragma unroll
            for (int r = 0; r < 4; ++r) {
                int bl  = hi * 4 + r;
                float fg = sigmoid_f(aAF[r] + biasF);
                float ig = sigmoid_f(aAI[r] + biasI);
                float gg = tanh_f(aAG[r] + biasG);
                float og = sigmoid_f(aAO[r] + biasO);
                cstA[r] = fg * cstA[r] + ig * gg;
                float h = og * tanh_f(cstA[r]);
                unsigned short hb =
                    (unsigned short)(((unsigned short)f2bf(h) & 0xFFFEu) | st);
                __hip_atomic_store(
                    reinterpret_cast<unsigned short*>(hd + bl * 32 + lrow * 2),
                    hb, __ATOMIC_RELAXED, __HIP_MEMORY_SCOPE_AGENT);
                outp[(size_t)(b0A + bl) * HID + j] = h;
                if (s == SEQ - 1) {
                    int gi = (b0A + bl) * HID + j;
                    hx[gi] = h; cxg[gi] = cstA[r];
                }
            }
        }

        // ---- check B stamps + retry
        {
            unsigned pend = 0;
            #pragma unroll
            for (int kc = 0; kc < 8; ++kc)
                if (!stamp_ok(bq0[kc], bq1[kc], ee)) pend |= (1u << kc);
            while (pend) {
                __builtin_amdgcn_s_sleep(1);
                #pragma unroll
                for (int kc = 0; kc < 8; ++kc) {
                    if (pend & (1u << kc)) {
                        const u64* pp = reinterpret_cast<const u64*>(
                            hsB + (2 * kc + (hi >> 1)) * REG_BYTES + lrow * 32 + (hi & 1) * 16);
                        bq0[kc] = __hip_atomic_load(pp,     __ATOMIC_RELAXED, __HIP_MEMORY_SCOPE_AGENT);
                        bq1[kc] = __hip_atomic_load(pp + 1, __ATOMIC_RELAXED, __HIP_MEMORY_SCOPE_AGENT);
                        if (stamp_ok(bq0[kc], bq1[kc], ee)) pend &= ~(1u << kc);
                    }
                }
            }
        }
        // ---- phase B_B
        #pragma unroll
        for (int kc = 0; kc < 8; ++kc) {
            union { u64 q[2]; bf16x8 v; } u;
            u.q[0] = bq0[kc]; u.q[1] = bq1[kc];
            aBF = __builtin_amdgcn_mfma_f32_16x16x32_bf16(u.v, wf[kc][0], aBF, 0, 0, 0);
            aBI = __builtin_amdgcn_mfma_f32_16x16x32_bf16(u.v, wf[kc][1], aBI, 0, 0, 0);
            aBG = __builtin_amdgcn_mfma_f32_16x16x32_bf16(u.v, wf[kc][2], aBG, 0, 0, 0);
            aBO = __builtin_amdgcn_mfma_f32_16x16x32_bf16(u.v, wf[kc][3], aBO, 0, 0, 0);
        }
        // ---- epilogue B
        {
            unsigned char* hd = regpB[(s + 1) & 1];
            #pragma unroll
            for (int r = 0; r < 4; ++r) {
                int bl  = hi * 4 + r;
                float fg = sigmoid_f(aBF[r] + biasF);
                float ig = sigmoid_f(aBI[r] + biasI);
                float gg = tanh_f(aBG[r] + biasG);
                float og = sigmoid_f(aBO[r] + biasO);
                cstB[r] = fg * cstB[r] + ig * gg;
                float h = og * tanh_f(cstB[r]);
                unsigned short hb =
                    (unsigned short)(((unsigned short)f2bf(h) & 0xFFFEu) | st);
                __hip_atomic_store(
                    reinterpret_cast<unsigned short*>(hd + bl * 32 + lrow * 2),
                    hb, __ATOMIC_RELAXED, __HIP_MEMORY_SCOPE_AGENT);
                outp[(size_t)(b0B + bl) * HID + j] = h;
                if (s == SEQ - 1) {
                    int gi = (b0B + bl) * HID + j;
                    hx[gi] = h; cxg[gi] = cstB[r];
                }
            }
        }
    }
}

extern "C" void kernel_launch(void* const* d_in, const int* in_sizes, int n_in,
                              void* d_out, int out_size, void* d_ws, size_t ws_size,
                              hipStream_t stream) {
    const float* x  = (const float*)d_in[0];
    const float* h0 = (const float*)d_in[1];
    const float* c0 = (const float*)d_in[2];
    const float* Wf = (const float*)d_in[3];
    const float* bf = (const float*)d_in[4];
    const float* Wi = (const float*)d_in[5];
    const float* bi = (const float*)d_in[6];
    const float* Wg = (const float*)d_in[7];
    const float* bg = (const float*)d_in[8];
    const float* Wo = (const float*)d_in[9];
    const float* bo = (const float*)d_in[10];

    float* out = (float*)d_out;
    float* hx  = out + (size_t)SEQ * BATCH * HID;
    float* cx  = hx + BATCH * HID;

    unsigned char* wb = (unsigned char*)d_ws;
    unsigned char* hr = wb + WB_BYTES;

    prep_w<<<256, 256, 0, stream>>>(Wf, Wi, Wg, Wo, wb);
    prep_h0<<<128, 256, 0, stream>>>(h0, hr);
    lstm_seq<<<128, 64, 65536, stream>>>(x, c0, bf, bi, bg, bo,
                                         wb, hr, out, hx, cx);
}

// Round 9
// 2502.334 us; speedup vs baseline: 2.1684x; 2.1684x over previous
//
#include <hip/hip_runtime.h>
#include <hip/hip_bf16.h>
#include <math.h>

#define SEQ   1024
#define BATCH 256
#define IND   256
#define HID   256
#define NGATE 4

// ws layout:
//   wb : bf16 [2 parts][4 gates][256 j][256 k], swizzled rows (1 MiB) @ 0
//   hr : bf16 regions [2 slots][16 g][16 J][16 b][16 j]; each 8B word's
//        element-0 LSB is the step stamp (512 B/region, single writer) @ 1 MiB
#define WB_BYTES   (2 * NGATE * HID * 256 * 2)
#define REG_BYTES  512

typedef float  f32x4  __attribute__((ext_vector_type(4)));
typedef short  bf16x8 __attribute__((ext_vector_type(8)));
typedef unsigned long long u64;

__device__ __forceinline__ short f2bf(float x) {
    __hip_bfloat16 h = __float2bfloat16(x);
    return *reinterpret_cast<short*>(&h);
}

__device__ __forceinline__ bf16x8 pack8(const float4& a, const float4& b) {
    union { short sh[8]; bf16x8 v; } u;
    u.sh[0] = f2bf(a.x); u.sh[1] = f2bf(a.y); u.sh[2] = f2bf(a.z); u.sh[3] = f2bf(a.w);
    u.sh[4] = f2bf(b.x); u.sh[5] = f2bf(b.y); u.sh[6] = f2bf(b.z); u.sh[7] = f2bf(b.w);
    return u.v;
}

__device__ __forceinline__ void gload_lds16(const void* g, void* l) {
    __builtin_amdgcn_global_load_lds(
        (const __attribute__((address_space(1))) unsigned int*)g,
        (__attribute__((address_space(3))) unsigned int*)l, 16, 0, 0);
}

__device__ __forceinline__ float sigmoid_f(float z) {
    return 1.f / (1.f + __expf(-z));
}
__device__ __forceinline__ float tanh_f(float v) {
    return 2.f / (1.f + __expf(-2.f * v)) - 1.f;
}

// word fresh iff element-0 LSB of both 8B words matches expected bit
__device__ __forceinline__ bool stamp_ok(u64 q0, u64 q1, u64 ee) {
    return ((((q0 ^ ee) | (q1 ^ ee)) & 1ULL) == 0ULL);
}

// ---------------- prep kernels ----------------

__global__ __launch_bounds__(256) void prep_w(
    const float* __restrict__ Wf, const float* __restrict__ Wi,
    const float* __restrict__ Wg, const float* __restrict__ Wo,
    unsigned char* __restrict__ wb)
{
    int chunk = blockIdx.x * 256 + threadIdx.x;   // 65536 chunks of 8 floats
    int g  = chunk >> 14;
    int jj = (chunk >> 6) & 255;
    int k0 = (chunk & 63) * 8;
    int p  = k0 >> 8;
    int kk = k0 & 255;
    const float* W = (g == 0) ? Wf : (g == 1) ? Wi : (g == 2) ? Wg : Wo;
    const float* src = W + (size_t)jj * 512 + k0;
    float4 a = *reinterpret_cast<const float4*>(src);
    float4 b = *reinterpret_cast<const float4*>(src + 4);
    size_t dstrow = (size_t)((p * 4 + g) * 256 + jj);
    *reinterpret_cast<bf16x8*>(
        wb + dstrow * 512 + ((kk * 2) ^ ((jj & 7) << 4))) = pack8(a, b);
}

// Seed both slots with stamp bit 1 in every element (so element-0 check sees 1):
// slot0 = h0 (occupant t=-1, expected stamp 1 at s=0 -> accepted);
// slot1 = dummy (expected stamp for its first occupant t=0 is 0 -> rejected).
__global__ __launch_bounds__(256) void prep_h0(
    const float* __restrict__ h0, unsigned char* __restrict__ hr)
{
    int idx  = blockIdx.x * 256 + threadIdx.x;    // 32768 chunks of 8 B
    int slot = idx >> 14;
    int g    = (idx >> 10) & 15;
    int J    = (idx >> 6) & 15;
    int c    = idx & 63;
    int br   = c >> 2;
    int j4   = (c & 3) * 4;
    const float* src = h0 + (size_t)(g * 16 + br) * HID + J * 16 + j4;
    unsigned short v[4];
    #pragma unroll
    for (int i = 0; i < 4; ++i)
        v[i] = (unsigned short)((unsigned short)f2bf(src[i]) | 1u);
    u64 q = (u64)v[0] | ((u64)v[1] << 16) | ((u64)v[2] << 32) | ((u64)v[3] << 48);
    *reinterpret_cast<u64*>(
        hr + (size_t)((slot * 16 + g) * 16 + J) * REG_BYTES + c * 8) = q;
}

// ---------------- persistent sequence kernel ----------------
// 256 blocks x 64 threads (1 wave). g_ = blk&15 (batch group; all 16 peers of
// a group share blk%8 -> same XCD under round-robin, perf heuristic only),
// J = blk>>4 (16 j-cols). W fragments resident in the unified RF all sequence;
// ZERO barriers and (steady-state) minimal LDS. Per step:
//   [issue h(s-1) word loads] [phase A: x-MFMA from regs] [pack x(s+1);
//   issue x(s+2)] [wait kc0-3 -> MFMA] [wait kc4-7 -> MFMA]
//   [epilogue: gates, c-regs; LDS transpose; ONE 8B stamped store/lane;
//    float4 out store/lane]
__global__ __launch_bounds__(64, 1) void lstm_seq(
    const float* __restrict__ x,  const float* __restrict__ c0,
    const float* __restrict__ bf_, const float* __restrict__ bi_,
    const float* __restrict__ bg_, const float* __restrict__ bo_,
    const unsigned char* __restrict__ wb, unsigned char* __restrict__ hr,
    float* __restrict__ out, float* __restrict__ hx, float* __restrict__ cxg)
{
    extern __shared__ __align__(16) unsigned char smem[];   // 64 KiB

    const int lane = threadIdx.x & 63;
    const int blk  = blockIdx.x;
    const int g_   = blk & 15;          // batch group (XCD-local peers)
    const int J    = blk >> 4;          // j-tile 0..15
    const int j0   = J * 16;
    const int b0   = g_ * 16;

    const int lrow = lane & 15;
    const int hi   = lane >> 4;
    const int j    = j0 + lrow;

    // ---- stage W tile (64 KiB) into LDS once
    #pragma unroll
    for (int i = 0; i < 64; ++i) {
        gload_lds16(wb + ((size_t)((i >> 3) * 256 + j0 + (i & 7) * 2)) * 512
                       + lane * 16,
                    smem + i * 1024);
    }
    const float biasF = bf_[j], biasI = bi_[j], biasG = bg_[j], biasO = bo_[j];
    float cst[4];
    #pragma unroll
    for (int r = 0; r < 4; ++r)
        cst[r] = c0[(b0 + hi * 4 + r) * HID + j];
    __syncthreads();    // drains gload_lds

    // ---- read all W fragments into the register file: wf[part][kc][gate]
    const int bswz = (lrow & 7) << 4;
    bf16x8 wf[2][8][4];
    #pragma unroll
    for (int p = 0; p < 2; ++p) {
        #pragma unroll
        for (int kc = 0; kc < 8; ++kc) {
            int wbyte = (kc * 64 + hi * 16) ^ bswz;
            #pragma unroll
            for (int gg = 0; gg < 4; ++gg)
                wf[p][kc][gg] = *reinterpret_cast<const bf16x8*>(
                    smem + p * 32768 + gg * 8192 + lrow * 512 + wbyte);
        }
    }
    // steady-state LDS: h stage [64 x 8B] @0, out stage [64 x 16B] @512

    // ---- x pipeline: xpk = packed x(s); xt = in-flight x(s+1)
    float4 xt0[8], xt1[8];
    bf16x8 xpk[8];
    {
        const float* xr = x + (size_t)(b0 + lrow) * IND;
        #pragma unroll
        for (int kc = 0; kc < 8; ++kc) {
            const float* p = xr + kc * 32 + hi * 8;
            xt0[kc] = *reinterpret_cast<const float4*>(p);
            xt1[kc] = *reinterpret_cast<const float4*>(p + 4);
        }
        #pragma unroll
        for (int kc = 0; kc < 8; ++kc) xpk[kc] = pack8(xt0[kc], xt1[kc]);
        const float* xr1 = x + ((size_t)BATCH + b0 + lrow) * IND;
        #pragma unroll
        for (int kc = 0; kc < 8; ++kc) {
            const float* p = xr1 + kc * 32 + hi * 8;
            xt0[kc] = *reinterpret_cast<const float4*>(p);
            xt1[kc] = *reinterpret_cast<const float4*>(p + 4);
        }
    }

    unsigned char* regc[2] = {
        hr + (size_t)((0 * 16 + g_) * 16) * REG_BYTES,
        hr + (size_t)((1 * 16 + g_) * 16) * REG_BYTES };
    unsigned char* regp[2] = { regc[0] + J * REG_BYTES, regc[1] + J * REG_BYTES };

    for (int s = 0; s < SEQ; ++s) {
        const u64 ee = (u64)(((unsigned)(s + 3) >> 1) & 1);   // expected stamp bit
        const unsigned char* hsrc = regc[s & 1];

        // ---- issue h(s-1) word loads (latency hides under phase A)
        u64 hq0[8], hq1[8];
        #pragma unroll
        for (int kc = 0; kc < 8; ++kc) {
            const u64* p = reinterpret_cast<const u64*>(
                hsrc + (2 * kc + (hi >> 1)) * REG_BYTES + lrow * 32 + (hi & 1) * 16);
            hq0[kc] = __hip_atomic_load(p,     __ATOMIC_RELAXED, __HIP_MEMORY_SCOPE_AGENT);
            hq1[kc] = __hip_atomic_load(p + 1, __ATOMIC_RELAXED, __HIP_MEMORY_SCOPE_AGENT);
        }
        __builtin_amdgcn_sched_barrier(0);

        // ---- phase A: x-part MFMA (pure register work)
        f32x4 aF = {0.f, 0.f, 0.f, 0.f};
        f32x4 aI = {0.f, 0.f, 0.f, 0.f};
        f32x4 aG = {0.f, 0.f, 0.f, 0.f};
        f32x4 aO = {0.f, 0.f, 0.f, 0.f};
        #pragma unroll
        for (int kc = 0; kc < 8; ++kc) {
            aF = __builtin_amdgcn_mfma_f32_16x16x32_bf16(xpk[kc], wf[0][kc][0], aF, 0, 0, 0);
            aI = __builtin_amdgcn_mfma_f32_16x16x32_bf16(xpk[kc], wf[0][kc][1], aI, 0, 0, 0);
            aG = __builtin_amdgcn_mfma_f32_16x16x32_bf16(xpk[kc], wf[0][kc][2], aG, 0, 0, 0);
            aO = __builtin_amdgcn_mfma_f32_16x16x32_bf16(xpk[kc], wf[0][kc][3], aO, 0, 0, 0);
        }

        // ---- pack x(s+1); issue x(s+2)  (filler inside the h RT)
        #pragma unroll
        for (int kc = 0; kc < 8; ++kc) xpk[kc] = pack8(xt0[kc], xt1[kc]);
        if (s + 2 < SEQ) {
            const float* xr = x + ((size_t)(s + 2) * BATCH + b0 + lrow) * IND;
            #pragma unroll
            for (int kc = 0; kc < 8; ++kc) {
                const float* p = xr + kc * 32 + hi * 8;
                xt0[kc] = *reinterpret_cast<const float4*>(p);
                xt1[kc] = *reinterpret_cast<const float4*>(p + 4);
            }
        }
        __builtin_amdgcn_sched_barrier(0);

        // ---- wait kc 0-3 -> MFMA; then kc 4-7 -> MFMA (arrival overlap)
        #pragma unroll
        for (int half = 0; half < 2; ++half) {
            const int kb = half * 4;
            unsigned pend = 0;
            #pragma unroll
            for (int kc = 0; kc < 4; ++kc)
                if (!stamp_ok(hq0[kb + kc], hq1[kb + kc], ee)) pend |= (1u << kc);
            while (pend) {
                #pragma unroll
                for (int kc = 0; kc < 4; ++kc) {
                    if (pend & (1u << kc)) {
                        const u64* p = reinterpret_cast<const u64*>(
                            hsrc + (2 * (kb + kc) + (hi >> 1)) * REG_BYTES
                                 + lrow * 32 + (hi & 1) * 16);
                        hq0[kb + kc] = __hip_atomic_load(p,     __ATOMIC_RELAXED, __HIP_MEMORY_SCOPE_AGENT);
                        hq1[kb + kc] = __hip_atomic_load(p + 1, __ATOMIC_RELAXED, __HIP_MEMORY_SCOPE_AGENT);
                        if (stamp_ok(hq0[kb + kc], hq1[kb + kc], ee)) pend &= ~(1u << kc);
                    }
                }
            }
            #pragma unroll
            for (int kc = 0; kc < 4; ++kc) {
                union { u64 q[2]; bf16x8 v; } u;
                u.q[0] = hq0[kb + kc]; u.q[1] = hq1[kb + kc];
                aF = __builtin_amdgcn_mfma_f32_16x16x32_bf16(u.v, wf[1][kb + kc][0], aF, 0, 0, 0);
                aI = __builtin_amdgcn_mfma_f32_16x16x32_bf16(u.v, wf[1][kb + kc][1], aI, 0, 0, 0);
                aG = __builtin_amdgcn_mfma_f32_16x16x32_bf16(u.v, wf[1][kb + kc][2], aG, 0, 0, 0);
                aO = __builtin_amdgcn_mfma_f32_16x16x32_bf16(u.v, wf[1][kb + kc][3], aO, 0, 0, 0);
            }
        }

        // ---- epilogue: gates + c update, stage h(bf16) and out(f32) in LDS
        float hv[4];
        #pragma unroll
        for (int r = 0; r < 4; ++r) {
            float fg = sigmoid_f(aF[r] + biasF);
            float ig = sigmoid_f(aI[r] + biasI);
            float gg = tanh_f(aG[r] + biasG);
            float og = sigmoid_f(aO[r] + biasO);
            cst[r] = fg * cst[r] + ig * gg;
            hv[r]  = og * tanh_f(cst[r]);
        }
        #pragma unroll
        for (int r = 0; r < 4; ++r) {
            int bl = hi * 4 + r;
            *reinterpret_cast<short*>(smem + bl * 32 + lrow * 2) = f2bf(hv[r]);
            *reinterpret_cast<float*>(smem + 512 + bl * 64 + lrow * 4) = hv[r];
        }
        __builtin_amdgcn_sched_barrier(0);
        asm volatile("s_waitcnt lgkmcnt(0)" ::: "memory");
        __builtin_amdgcn_sched_barrier(0);

        // ---- ONE stamped 8B store per lane (critical), then 16B out store
        {
            u64 w = *reinterpret_cast<const u64*>(smem + lane * 8);
            w = (w & ~1ULL) | (u64)((s >> 1) & 1);          // stamp elem-0 LSB
            __hip_atomic_store(
                reinterpret_cast<u64*>(regp[(s + 1) & 1] + lane * 8),
                w, __ATOMIC_RELAXED, __HIP_MEMORY_SCOPE_AGENT);
        }
        {
            float4 ov = *reinterpret_cast<const float4*>(smem + 512 + lane * 16);
            *reinterpret_cast<float4*>(
                out + (size_t)s * (BATCH * HID)
                    + (size_t)(b0 + (lane >> 2)) * HID + j0 + (lane & 3) * 4) = ov;
        }
        if (s == SEQ - 1) {
            #pragma unroll
            for (int r = 0; r < 4; ++r) {
                int gi = (b0 + hi * 4 + r) * HID + j;
                hx[gi] = hv[r]; cxg[gi] = cst[r];
            }
        }
    }
}

extern "C" void kernel_launch(void* const* d_in, const int* in_sizes, int n_in,
                              void* d_out, int out_size, void* d_ws, size_t ws_size,
                              hipStream_t stream) {
    const float* x  = (const float*)d_in[0];
    const float* h0 = (const float*)d_in[1];
    const float* c0 = (const float*)d_in[2];
    const float* Wf = (const float*)d_in[3];
    const float* bf = (const float*)d_in[4];
    const float* Wi = (const float*)d_in[5];
    const float* bi = (const float*)d_in[6];
    const float* Wg = (const float*)d_in[7];
    const float* bg = (const float*)d_in[8];
    const float* Wo = (const float*)d_in[9];
    const float* bo = (const float*)d_in[10];

    float* out = (float*)d_out;
    float* hx  = out + (size_t)SEQ * BATCH * HID;
    float* cx  = hx + BATCH * HID;

    unsigned char* wb = (unsigned char*)d_ws;
    unsigned char* hr = wb + WB_BYTES;

    prep_w<<<256, 256, 0, stream>>>(Wf, Wi, Wg, Wo, wb);
    prep_h0<<<128, 256, 0, stream>>>(h0, hr);
    lstm_seq<<<256, 64, 65536, stream>>>(x, c0, bf, bi, bg, bo,
                                         wb, hr, out, hx, cx);
}